// Round 14
// baseline (32.703 us; speedup 1.0000x reference)
//
#include <hip/hip_runtime.h>
#include <hip/hip_bf16.h>

// Problem constants (match reference)
constexpr int P = 8192;
constexpr int G = 4096;
constexpr int BLK = 256;
constexpr int GSPLIT = 256;         // G-dimension parallel chunks
constexpr int CHUNK = G / GSPLIT;   // 16 gaussians per chunk
constexpr int PPT = 8;              // points per thread (4 packed halves)
constexpr int NH = PPT / 2;         // packed halves
constexpr int PBLK = BLK * PPT;     // 2048 points per block
constexpr float LOG2E = 1.4426950408889634f;

// Packed fp32 pair: gfx950 VOP3P v_pk_{fma,mul,add}_f32 (verified -3.8us R12).
typedef float v2f __attribute__((ext_vector_type(2)));

// Single-instruction exp2 (v_exp_f32 IS 2^x; verified -4us in R9).
__device__ __forceinline__ float fast_exp2(float x) {
  float r;
  asm("v_exp_f32 %0, %1" : "=v"(r) : "v"(x));
  return r;
}

// ---------------------------------------------------------------------------
// Fused kernel. Grid = (P/PBLK, GSPLIT) = (4, 256) = 1024 blocks, 4/CU,
// 4 waves/SIMD. R12 vs R13 isolated: LDS-throughput NOT binding (halving it
// was flat), but 2 waves/SIMD exposes the ds_read->6FMA->exp2 chain. This
// config keeps PPT=8's low LDS demand AND 4 waves/SIMD (the stall-hiding
// R13 gave up). Total ds_reads unchanged vs R13; partial 8MB.
// Per-gaussian coefficients (5 x float4 in LDS, broadcast ds_read_b128):
//   v0: mean.x, mean.y, mean.z, w00
//   v1: w11, w22, w01, w02
//   v2: w12, a0, a1, a2
//   v3: a3, qxy, qyz, qxz
//   v4: qxx, qyy, qzz, 0
// gauss = exp2(w00 dxx + w11 dyy + w22 dzz + w01 dxdy + w02 dxdz + w12 dydz)
// feat  = a0 + inv*lin + inv2*quad  (SH on the same 6 monomials)
// ---------------------------------------------------------------------------
__global__ __launch_bounds__(BLK) void fused_main(
    const float* __restrict__ pos,
    const float* __restrict__ mean, const float* __restrict__ fdc,
    const float* __restrict__ frest, const float* __restrict__ scal,
    const float* __restrict__ rot, const float* __restrict__ opac,
    float* __restrict__ partial) {
  __shared__ float4 sg[CHUNK * 5];

  const int t = threadIdx.x;
  const int c = blockIdx.y;
  const int pbase = blockIdx.x * PBLK + t;

  // Points packed in pairs; loads issued first to overlap the precompute.
  v2f pxv[NH], pyv[NH], pzv[NH], accv[NH];
#pragma unroll
  for (int h = 0; h < NH; ++h) {
    const int pA = pbase + (2 * h + 0) * BLK;
    const int pB = pbase + (2 * h + 1) * BLK;
    v2f x = {pos[pA * 3 + 0], pos[pB * 3 + 0]};
    v2f y = {pos[pA * 3 + 1], pos[pB * 3 + 1]};
    v2f z = {pos[pA * 3 + 2], pos[pB * 3 + 2]};
    pxv[h] = x * 2.0f - 1.0f;
    pyv[h] = y * 2.0f - 1.0f;
    pzv[h] = z * 2.0f - 1.0f;
    accv[h] = (v2f){0.f, 0.f};
  }

  // In-block precompute of this chunk's 16 gaussians (8x redundant across
  // blockIdx.x; ~500 cycles, negligible).
  if (t < CHUNK) {
    const int g = c * CHUNK + t;

    float qr = rot[g * 4 + 0], qx = rot[g * 4 + 1];
    float qy = rot[g * 4 + 2], qz = rot[g * 4 + 3];
    float qn = 1.0f / sqrtf(qr * qr + qx * qx + qy * qy + qz * qz);
    qr *= qn; qx *= qn; qy *= qn; qz *= qn;

    float R00 = 1.f - 2.f * (qy * qy + qz * qz);
    float R01 = 2.f * (qx * qy - qr * qz);
    float R02 = 2.f * (qx * qz + qr * qy);
    float R10 = 2.f * (qx * qy + qr * qz);
    float R11 = 1.f - 2.f * (qx * qx + qz * qz);
    float R12 = 2.f * (qy * qz - qr * qx);
    float R20 = 2.f * (qx * qz - qr * qy);
    float R21 = 2.f * (qy * qz + qr * qx);
    float R22 = 1.f - 2.f * (qx * qx + qy * qy);

    float sc0 = expf(scal[g * 3 + 0]);
    float sc1 = expf(scal[g * 3 + 1]);
    float sc2 = expf(scal[g * 3 + 2]);
    float iv0 = 1.0f / (sc0 * sc0);
    float iv1 = 1.0f / (sc1 * sc1);
    float iv2 = 1.0f / (sc2 * sc2);

    float s00 = R00 * R00 * iv0 + R01 * R01 * iv1 + R02 * R02 * iv2;
    float s11 = R10 * R10 * iv0 + R11 * R11 * iv1 + R12 * R12 * iv2;
    float s22 = R20 * R20 * iv0 + R21 * R21 * iv1 + R22 * R22 * iv2;
    float s01 = R00 * R10 * iv0 + R01 * R11 * iv1 + R02 * R12 * iv2;
    float s02 = R00 * R20 * iv0 + R01 * R21 * iv1 + R02 * R22 * iv2;
    float s12 = R10 * R20 * iv0 + R11 * R21 * iv1 + R12 * R22 * iv2;

    const float kD = -0.5f * LOG2E;
    const float kO = -LOG2E;

    float alpha = 1.0f / (1.0f + expf(-opac[g]));

    const float C0 = 0.28209479177387814f;
    const float C1 = 0.4886025119029199f;
    float a0 = C0 * fdc[g] * alpha;
    float a1 = -C1 * frest[g * 8 + 0] * alpha;
    float a2 =  C1 * frest[g * 8 + 1] * alpha;
    float a3 = -C1 * frest[g * 8 + 2] * alpha;
    float a4 =  1.0925484305920792f  * frest[g * 8 + 3] * alpha;
    float a5 = -1.0925484305920792f  * frest[g * 8 + 4] * alpha;
    float a6 =  0.31539156525252005f * frest[g * 8 + 5] * alpha;
    float a7 = -1.0925484305920792f  * frest[g * 8 + 6] * alpha;
    float a8 =  0.5462742152960396f  * frest[g * 8 + 7] * alpha;

    float mx = mean[g * 3 + 0], my = mean[g * 3 + 1], mz = mean[g * 3 + 2];

    sg[t * 5 + 0] = make_float4(mx, my, mz, kD * s00);
    sg[t * 5 + 1] = make_float4(kD * s11, kD * s22, kO * s01, kO * s02);
    sg[t * 5 + 2] = make_float4(kO * s12, a0, a1, a2);
    sg[t * 5 + 3] = make_float4(a3, a4, a5, a7);                    // a3,qxy,qyz,qxz
    sg[t * 5 + 4] = make_float4(a8 - a6, -a8 - a6, 2.f * a6, 0.f);  // qxx,qyy,qzz
  }

  __syncthreads();

#pragma unroll 2
  for (int gi = 0; gi < CHUNK; ++gi) {
    const float4 v0 = sg[gi * 5 + 0];
    const float4 v1 = sg[gi * 5 + 1];
    const float4 v2 = sg[gi * 5 + 2];
    const float4 v3 = sg[gi * 5 + 3];
    const float4 v4 = sg[gi * 5 + 4];

#pragma unroll
    for (int h = 0; h < NH; ++h) {
      // scalar coefficients splat across the packed pair -> v_pk_* ops
      const v2f dx = pxv[h] - v0.x;
      const v2f dy = pyv[h] - v0.y;
      const v2f dz = pzv[h] - v0.z;
      const v2f dxx = dx * dx, dyy = dy * dy, dzz = dz * dz;
      const v2f dxdy = dx * dy, dxdz = dx * dz, dydz = dy * dz;
      const v2f d2 = dxx + dyy + dzz;

      v2f m = v0.w * dxx;
      m = v1.x * dyy + m;
      m = v1.y * dzz + m;
      m = v1.z * dxdy + m;
      m = v1.w * dxdz + m;
      m = v2.x * dydz + m;
      v2f gauss;
      gauss.x = fast_exp2(m.x);
      gauss.y = fast_exp2(m.y);

      const v2f d2c = __builtin_elementwise_max(d2, (v2f){1e-16f, 1e-16f});
      v2f inv;
      inv.x = __builtin_amdgcn_rsqf(d2c.x);
      inv.y = __builtin_amdgcn_rsqf(d2c.y);
      const v2f inv2 = inv * inv;

      v2f lin = v2.z * dy;                 // a1*dy
      lin = v2.w * dz + lin;               // a2*dz
      lin = v3.x * dx + lin;               // a3*dx

      v2f quad = v3.y * dxdy;              // qxy*dxdy
      quad = v3.z * dydz + quad;           // qyz*dydz
      quad = v3.w * dxdz + quad;           // qxz*dxdz
      quad = v4.x * dxx + quad;            // qxx*dxx
      quad = v4.y * dyy + quad;            // qyy*dyy
      quad = v4.z * dzz + quad;            // qzz*dzz

      v2f feat = inv * lin + v2.y;         // a0 + inv*lin
      feat = inv2 * quad + feat;

      accv[h] = gauss * feat + accv[h];
    }
  }

#pragma unroll
  for (int h = 0; h < NH; ++h) {
    partial[(size_t)c * P + pbase + (2 * h + 0) * BLK] = accv[h].x;
    partial[(size_t)c * P + pbase + (2 * h + 1) * BLK] = accv[h].y;
  }
}

// ---------------------------------------------------------------------------
// Two-level parallel reduction over GSPLIT=256 partials (R8's proven shape).
// 128 blocks x 512 thr; slice s = t>>6 (8 slices) sums contiguous c-range
// [s*32, s*32+32) for point p = blk*64 + (t&63), 4 accumulator chains.
// Fixed combine order -> deterministic.
// ---------------------------------------------------------------------------
__global__ __launch_bounds__(512) void reduce_kernel(
    const float* __restrict__ partial, float* __restrict__ out) {
  __shared__ float red[8][64];
  const int t = threadIdx.x;
  const int lane = t & 63;
  const int s = t >> 6;
  const int p = blockIdx.x * 64 + lane;
  const int cbase = s * 32;

  float a0 = 0.f, a1 = 0.f, a2 = 0.f, a3 = 0.f;
#pragma unroll
  for (int j = 0; j < 32; j += 4) {
    a0 += partial[(size_t)(cbase + j + 0) * P + p];
    a1 += partial[(size_t)(cbase + j + 1) * P + p];
    a2 += partial[(size_t)(cbase + j + 2) * P + p];
    a3 += partial[(size_t)(cbase + j + 3) * P + p];
  }
  red[s][lane] = (a0 + a1) + (a2 + a3);
  __syncthreads();

  if (t < 64) {
    float r = 0.f;
#pragma unroll
    for (int s2 = 0; s2 < 8; ++s2) r += red[s2][lane];
    out[p] = r;
  }
}

extern "C" void kernel_launch(void* const* d_in, const int* in_sizes, int n_in,
                              void* d_out, int out_size, void* d_ws, size_t ws_size,
                              hipStream_t stream) {
  const float* pos   = (const float*)d_in[0];  // position_rx (P,3)
  const float* mean  = (const float*)d_in[1];  // mean (G,3)
  const float* fdc   = (const float*)d_in[2];  // features_dc (G,1,1)
  const float* frest = (const float*)d_in[3];  // features_rest (G,1,8)
  const float* scal  = (const float*)d_in[4];  // scaling (G,3)
  const float* rot   = (const float*)d_in[5];  // rotation (G,4)
  const float* opac  = (const float*)d_in[6];  // opacity (G,1)
  float* out = (float*)d_out;                  // (P,1) fp32

  float* partial = (float*)d_ws;               // GSPLIT*P*4 = 8 MB

  fused_main<<<dim3(P / PBLK, GSPLIT), BLK, 0, stream>>>(
      pos, mean, fdc, frest, scal, rot, opac, partial);
  reduce_kernel<<<P / 64, 512, 0, stream>>>(partial, out);
}